// Round 1
// baseline (1055.723 us; speedup 1.0000x reference)
//
#include <hip/hip_runtime.h>
#include <hip/hip_bf16.h>

// DynaLoRALinear: out[b,l,o] = sum_k x[b,l,k] W_base[o,k] + b_base[o]
//                            + sum_{e,r} gate[b,e] * (sum_i x[b,l,i] A[e,r,i]) * Bm[e,o,r]
// Strategy: augment K — x_aug[row][0:4096]=bf16(x), [4096:4128]=gate*t, [4128:4160]=0
//           W_aug[o][0:4096]=bf16(W_base), [4096+e*8+r]=bf16(lora_B[e,o,r]), rest 0
// Single bf16 MFMA GEMM M=16384 N=4096 K=4160 (m97-style 128x128 tile, BK=64).

typedef short short8 __attribute__((ext_vector_type(8)));
typedef float f32x4v __attribute__((ext_vector_type(4)));

#define M_DIM 16384
#define N_DIM 4096
#define K_DIM 4160   // 4096 + 64 (32 lora cols + 32 zero pad); 65*64
#define D_DIM 4096

__device__ __forceinline__ unsigned short f2b(float f) {
  unsigned u = __builtin_bit_cast(unsigned, f);
  return (unsigned short)((u + 0x7FFFu + ((u >> 16) & 1u)) >> 16);  // RNE
}
__device__ __forceinline__ float bf2f(unsigned short u) {
  unsigned v = ((unsigned)u) << 16;
  return __builtin_bit_cast(float, v);
}
__device__ __forceinline__ void async_copy16(void* lds, const void* g) {
  __builtin_amdgcn_global_load_lds(
      (const __attribute__((address_space(1))) void*)g,
      (__attribute__((address_space(3))) void*)lds, 16, 0, 0);
}

// ---- K1: convert x (f32) -> x_aug (bf16, stride 4160), zero cols 4096..4159
__global__ __launch_bounds__(256) void cvt_x_k(const float* __restrict__ x,
                                               short* __restrict__ xa) {
  size_t idx = (size_t)blockIdx.x * 256 + threadIdx.x;   // 16384*520 total
  size_t row = idx / 520;
  int cc = (int)(idx % 520);
  short8 o;
  if (cc < 512) {
    const float* src = x + row * (size_t)D_DIM + (size_t)cc * 8;
    float4 a = *(const float4*)(src);
    float4 b = *(const float4*)(src + 4);
    o[0] = (short)f2b(a.x); o[1] = (short)f2b(a.y);
    o[2] = (short)f2b(a.z); o[3] = (short)f2b(a.w);
    o[4] = (short)f2b(b.x); o[5] = (short)f2b(b.y);
    o[6] = (short)f2b(b.z); o[7] = (short)f2b(b.w);
  } else {
#pragma unroll
    for (int t = 0; t < 8; ++t) o[t] = 0;
  }
  *(short8*)(xa + row * (size_t)K_DIM + (size_t)cc * 8) = o;
}

// ---- K2: convert W_base -> W_aug, pack lora_B into cols 4096..4127, zero rest
__global__ __launch_bounds__(256) void cvt_w_k(const float* __restrict__ Wb,
                                               const float* __restrict__ lB,
                                               short* __restrict__ wa) {
  size_t idx = (size_t)blockIdx.x * 256 + threadIdx.x;   // 4096*520 total
  size_t row = idx / 520;
  int cc = (int)(idx % 520);
  short8 o;
  if (cc < 512) {
    const float* src = Wb + row * (size_t)D_DIM + (size_t)cc * 8;
    float4 a = *(const float4*)(src);
    float4 b = *(const float4*)(src + 4);
    o[0] = (short)f2b(a.x); o[1] = (short)f2b(a.y);
    o[2] = (short)f2b(a.z); o[3] = (short)f2b(a.w);
    o[4] = (short)f2b(b.x); o[5] = (short)f2b(b.y);
    o[6] = (short)f2b(b.z); o[7] = (short)f2b(b.w);
  } else if (cc < 516) {
    int e = cc - 512;                                     // col 4096+e*8+r = lora_B[e][row][r]
    const float* src = lB + (size_t)e * (D_DIM * 8) + row * 8;
    float4 a = *(const float4*)(src);
    float4 b = *(const float4*)(src + 4);
    o[0] = (short)f2b(a.x); o[1] = (short)f2b(a.y);
    o[2] = (short)f2b(a.z); o[3] = (short)f2b(a.w);
    o[4] = (short)f2b(b.x); o[5] = (short)f2b(b.y);
    o[6] = (short)f2b(b.z); o[7] = (short)f2b(b.w);
  } else {
#pragma unroll
    for (int t = 0; t < 8; ++t) o[t] = 0;
  }
  *(short8*)(wa + row * (size_t)K_DIM + (size_t)cc * 8) = o;
}

// ---- K3: gated[b][j] = dot(x[b, L-1, :], gating_W[j, :])   (f32, exact path)
__global__ __launch_bounds__(256) void gated_k(const float* __restrict__ x,
                                               const float* __restrict__ gW,
                                               float* __restrict__ gated) {
  const int j = blockIdx.x;          // 0..4095
  const int tid = threadIdx.x;
  float acc[8];
#pragma unroll
  for (int b = 0; b < 8; ++b) acc[b] = 0.f;
  const float* w = gW + (size_t)j * D_DIM;
  for (int i = tid * 4; i < D_DIM; i += 1024) {
    float4 wv = *(const float4*)(w + i);
#pragma unroll
    for (int b = 0; b < 8; ++b) {
      const float* p = x + ((size_t)b * 2048 + 2047) * D_DIM + i;
      float4 pv = *(const float4*)p;
      acc[b] += wv.x * pv.x + wv.y * pv.y + wv.z * pv.z + wv.w * pv.w;
    }
  }
  __shared__ float red[8][4];
  const int lane = tid & 63, wv_ = tid >> 6;
#pragma unroll
  for (int b = 0; b < 8; ++b) {
    float v = acc[b];
    v += __shfl_down(v, 32); v += __shfl_down(v, 16); v += __shfl_down(v, 8);
    v += __shfl_down(v, 4);  v += __shfl_down(v, 2);  v += __shfl_down(v, 1);
    if (lane == 0) red[b][wv_] = v;
  }
  __syncthreads();
  if (tid < 8)
    gated[(size_t)tid * D_DIM + j] = red[tid][0] + red[tid][1] + red[tid][2] + red[tid][3];
}

// ---- K4: logits -> softmax -> module_prob -> top-k gate (1 wave)
__global__ void gate_k(const float* __restrict__ gated, const float* __restrict__ Wr,
                       const float* __restrict__ scores, const int* __restrict__ midx_p,
                       const int* __restrict__ kp, float* __restrict__ gate) {
  const int lane = threadIdx.x;      // 64 threads
  float acc[56];
#pragma unroll
  for (int t = 0; t < 56; ++t) acc[t] = 0.f;
  for (int i = lane * 4; i < D_DIM; i += 256) {
    float4 g[8]; float4 w[7];
#pragma unroll
    for (int b = 0; b < 8; ++b) g[b] = *(const float4*)(gated + (size_t)b * D_DIM + i);
#pragma unroll
    for (int m = 0; m < 7; ++m) w[m] = *(const float4*)(Wr + (size_t)m * D_DIM + i);
#pragma unroll
    for (int m = 0; m < 7; ++m)
#pragma unroll
      for (int b = 0; b < 8; ++b)
        acc[m * 8 + b] += w[m].x * g[b].x + w[m].y * g[b].y + w[m].z * g[b].z + w[m].w * g[b].w;
  }
  __shared__ float Ls[56];
#pragma unroll
  for (int t = 0; t < 56; ++t) {
    float v = acc[t];
    v += __shfl_xor(v, 1); v += __shfl_xor(v, 2); v += __shfl_xor(v, 4);
    v += __shfl_xor(v, 8); v += __shfl_xor(v, 16); v += __shfl_xor(v, 32);
    if (lane == t) Ls[t] = v;
  }
  __syncthreads();
  if (lane < 8) {
    const int b = lane;
    float mx = -1e30f;
    for (int m = 0; m < 7; ++m) mx = fmaxf(mx, Ls[m * 8 + b]);
    float s = 0.f;
    for (int m = 0; m < 7; ++m) s += expf(Ls[m * 8 + b] - mx);
    const int mi = midx_p[0];
    const float mp = expf(Ls[mi * 8 + b] - mx) / s;
    int kv = kp[0]; if (kv < 1) kv = 1;
    int klo = kv >> 1; if (klo < 1) klo = 1;
    float sc[4];
#pragma unroll
    for (int e = 0; e < 4; ++e) sc[e] = scores[b * 4 + e];
#pragma unroll
    for (int e = 0; e < 4; ++e) {
      int rank = 0;
#pragma unroll
      for (int e2 = 0; e2 < 4; ++e2)
        rank += (sc[e2] > sc[e] || (sc[e2] == sc[e] && e2 < e)) ? 1 : 0;
      float wv = (mp > 0.5f) ? ((rank < kv) ? 1.0f / (float)kv : 0.f)
                             : ((rank < klo) ? 1.0f / (float)klo : 0.f);
      gate[b * 4 + e] = wv;
    }
  }
}

// ---- K5: t'[row][er] = gate[b][e] * dot(x_row, lora_A[e,r,:]) -> x_aug cols 4096..4127
// block = 16 rows x 16 k-slices; lanes 0..15 of each 16-group share a row.
__global__ __launch_bounds__(256) void lora_t_k(const short* __restrict__ xa,
                                                const float* __restrict__ lA,
                                                const float* __restrict__ gate,
                                                short* __restrict__ xa_w) {
  const int tid = threadIdx.x;
  const int rl = tid >> 4;           // local row 0..15
  const int lp = tid & 15;           // k-slot
  const size_t row = (size_t)blockIdx.x * 16 + rl;
  float acc[32];
#pragma unroll
  for (int er = 0; er < 32; ++er) acc[er] = 0.f;
  const short* xrow = xa + row * (size_t)K_DIM;
  for (int j = 0; j < 32; ++j) {
    const int k = lp * 8 + j * 128;
    short8 xv = *(const short8*)(xrow + k);
    float xf[8];
#pragma unroll
    for (int t = 0; t < 8; ++t) xf[t] = bf2f((unsigned short)xv[t]);
#pragma unroll
    for (int er = 0; er < 32; ++er) {
      const float* ap = lA + (size_t)er * D_DIM + k;
      float4 a0 = *(const float4*)ap;
      float4 a1 = *(const float4*)(ap + 4);
      acc[er] += xf[0] * a0.x + xf[1] * a0.y + xf[2] * a0.z + xf[3] * a0.w
               + xf[4] * a1.x + xf[5] * a1.y + xf[6] * a1.z + xf[7] * a1.w;
    }
  }
#pragma unroll
  for (int er = 0; er < 32; ++er) {
    float v = acc[er];
    v += __shfl_xor(v, 1); v += __shfl_xor(v, 2);
    v += __shfl_xor(v, 4); v += __shfl_xor(v, 8);
    acc[er] = v;
  }
  if (lp == 0) {
    const int b = (int)(row >> 11);  // row / 2048
#pragma unroll
    for (int er = 0; er < 32; ++er) {
      float g = gate[b * 4 + (er >> 3)];
      xa_w[row * (size_t)K_DIM + 4096 + er] = (short)f2b(acc[er] * g);
    }
  }
}

// ---- K6: main GEMM: C[M][N] = A[M][K] * B[N][K]^T + bias, bf16 MFMA 16x16x32
// 128x128 tile, BK=64, 256 threads (4 waves of 64x64), global_load_lds width 16.
__global__ __launch_bounds__(256) void gemm_k(const short* __restrict__ A,
                                              const short* __restrict__ B,
                                              const float* __restrict__ bias,
                                              float* __restrict__ C) {
  __shared__ short As[128 * 64];
  __shared__ short Bs[128 * 64];
  const int tid  = threadIdx.x;
  const int lane = tid & 63;
  const int wave = tid >> 6;
  const int wm = wave >> 1, wn = wave & 1;
  const int brow = blockIdx.x >> 5;   // M/128 = 128 rows of tiles, N/128 = 32 cols
  const int bcol = blockIdx.x & 31;
  const int lo = lane & 15, hi = lane >> 4;

  f32x4v acc[4][4] = {};

  const int ch = tid & 7;             // 16B chunk within 64-col row
  const int rr = tid >> 3;            // staging row 0..31 (per p: +32)
  const short* gA = A + (size_t)(brow * 128 + rr) * K_DIM + ch * 8;
  const short* gB = B + (size_t)(bcol * 128 + rr) * K_DIM + ch * 8;
  char* ldsA = (char*)As + wave * 1024;  // + p*4096; lanes write +lane*16
  char* ldsB = (char*)Bs + wave * 1024;

  for (int kt = 0; kt < K_DIM; kt += 64) {
#pragma unroll
    for (int p = 0; p < 4; ++p) {
      async_copy16(ldsA + p * 4096, gA + (size_t)p * 32 * K_DIM + kt);
      async_copy16(ldsB + p * 4096, gB + (size_t)p * 32 * K_DIM + kt);
    }
    __syncthreads();   // compiler drains vmcnt(0) before barrier -> tiles ready
#pragma unroll
    for (int kk = 0; kk < 64; kk += 32) {
      short8 af[4], bf[4];
#pragma unroll
      for (int mi = 0; mi < 4; ++mi)
        af[mi] = *(const short8*)(&As[(wm * 64 + mi * 16 + lo) * 64 + kk + hi * 8]);
#pragma unroll
      for (int ni = 0; ni < 4; ++ni)
        bf[ni] = *(const short8*)(&Bs[(wn * 64 + ni * 16 + lo) * 64 + kk + hi * 8]);
#pragma unroll
      for (int mi = 0; mi < 4; ++mi)
#pragma unroll
        for (int ni = 0; ni < 4; ++ni)
          acc[mi][ni] = __builtin_amdgcn_mfma_f32_16x16x32_bf16(af[mi], bf[ni], acc[mi][ni], 0, 0, 0);
    }
    __syncthreads();   // all waves done reading before next stage overwrites
  }

#pragma unroll
  for (int mi = 0; mi < 4; ++mi) {
#pragma unroll
    for (int ni = 0; ni < 4; ++ni) {
      const int r0 = brow * 128 + wm * 64 + mi * 16 + hi * 4;
      const int c0 = bcol * 128 + wn * 64 + ni * 16 + lo;
      const float bz = bias[c0];
#pragma unroll
      for (int j = 0; j < 4; ++j)
        C[(size_t)(r0 + j) * N_DIM + c0] = acc[mi][ni][j] + bz;
    }
  }
}

extern "C" void kernel_launch(void* const* d_in, const int* in_sizes, int n_in,
                              void* d_out, int out_size, void* d_ws, size_t ws_size,
                              hipStream_t stream) {
  const float* x      = (const float*)d_in[0];
  const float* scores = (const float*)d_in[1];
  const float* Wb     = (const float*)d_in[2];
  const float* bb     = (const float*)d_in[3];
  const float* gW     = (const float*)d_in[4];
  const float* Wr     = (const float*)d_in[5];
  const float* lA     = (const float*)d_in[6];
  const float* lB     = (const float*)d_in[7];
  const int*   midx   = (const int*)d_in[8];
  const int*   kk     = (const int*)d_in[9];
  float* out = (float*)d_out;

  char* ws = (char*)d_ws;
  short* xa    = (short*)ws;                               // 16384*4160*2 = 136,314,880 B
  short* wa    = (short*)(ws + 136314880u);                // 4096*4160*2 = 34,078,720 B
  float* gated = (float*)(ws + 136314880u + 34078720u);    // 8*4096*4 = 131,072 B
  float* gate  = (float*)(ws + 136314880u + 34078720u + 131072u);  // 32*4 B

  cvt_x_k<<<33280, 256, 0, stream>>>(x, xa);
  cvt_w_k<<<8320, 256, 0, stream>>>(Wb, lB, wa);
  gated_k<<<4096, 256, 0, stream>>>(x, gW, gated);
  gate_k<<<1, 64, 0, stream>>>(gated, Wr, scores, midx, kk, gate);
  lora_t_k<<<1024, 256, 0, stream>>>(xa, lA, gate, xa);
  gemm_k<<<4096, 256, 0, stream>>>(xa, wa, bb, out);
}

// Round 3
// 805.812 us; speedup vs baseline: 1.3101x; 1.3101x over previous
//
#include <hip/hip_runtime.h>
#include <hip/hip_bf16.h>

// DynaLoRALinear via K-augmented bf16 GEMM:
//   x_aug[row][0:4096]=bf16(x), [4096:4128]=gate*t (from LoRA-A MFMA GEMM), [4128:4160]=0
//   W_aug[o][0:4096]=bf16(W_base), [4096+e*8+r]=bf16(lora_B[e,o,r]), rest 0
//   out = x_aug @ W_aug^T + b_base   (M=16384, N=4096, K=4160)
// Main GEMM: 256x256 tile, BK=64, 8 waves, double-buffered LDS, counted vmcnt(8)
// (prefetch loads stay in flight across raw s_barrier), XOR slot-swizzle (T2),
// setprio (T5), XCD-aware block swizzle (T1).

typedef short short8 __attribute__((ext_vector_type(8)));
typedef float f32x4v __attribute__((ext_vector_type(4)));

#define M_DIM 16384
#define N_DIM 4096
#define K_DIM 4160   // 65 * 64
#define D_DIM 4096

__device__ __forceinline__ unsigned short f2b(float f) {
  unsigned u = __builtin_bit_cast(unsigned, f);
  return (unsigned short)((u + 0x7FFFu + ((u >> 16) & 1u)) >> 16);  // RNE
}
__device__ __forceinline__ void async_copy16(void* lds, const void* g) {
  __builtin_amdgcn_global_load_lds(
      (const __attribute__((address_space(1))) void*)g,
      (__attribute__((address_space(3))) void*)lds, 16, 0, 0);
}
// LDS tile layout: row-major [rows][64] bf16 (128 B/row = 8 x 16B slots).
// Physical slot p of row r holds logical slot l = p ^ (r&7) (written via
// pre-swizzled global source). Read of logical slot l: p = l ^ (r&7).
__device__ __forceinline__ short8 frag_ld(const short* base, int row, int ks, int hi, int lo) {
  return *(const short8*)(&base[row * 64 + (((ks * 4 + hi) ^ (lo & 7)) * 8)]);
}

// ---- K1: x (f32) -> x_aug (bf16, stride 4160), zero cols 4096..4159
__global__ __launch_bounds__(256) void cvt_x_k(const float* __restrict__ x,
                                               short* __restrict__ xa) {
  size_t idx = (size_t)blockIdx.x * 256 + threadIdx.x;   // 16384*520
  size_t row = idx / 520;
  int cc = (int)(idx % 520);
  short8 o;
  if (cc < 512) {
    const float* src = x + row * (size_t)D_DIM + (size_t)cc * 8;
    float4 a = *(const float4*)(src);
    float4 b = *(const float4*)(src + 4);
    o[0] = (short)f2b(a.x); o[1] = (short)f2b(a.y);
    o[2] = (short)f2b(a.z); o[3] = (short)f2b(a.w);
    o[4] = (short)f2b(b.x); o[5] = (short)f2b(b.y);
    o[6] = (short)f2b(b.z); o[7] = (short)f2b(b.w);
  } else {
#pragma unroll
    for (int t = 0; t < 8; ++t) o[t] = 0;
  }
  *(short8*)(xa + row * (size_t)K_DIM + (size_t)cc * 8) = o;
}

// ---- K2: W_base -> W_aug, pack lora_B into cols 4096..4127, zero rest
__global__ __launch_bounds__(256) void cvt_w_k(const float* __restrict__ Wb,
                                               const float* __restrict__ lB,
                                               short* __restrict__ wa) {
  size_t idx = (size_t)blockIdx.x * 256 + threadIdx.x;   // 4096*520
  size_t row = idx / 520;
  int cc = (int)(idx % 520);
  short8 o;
  if (cc < 512) {
    const float* src = Wb + row * (size_t)D_DIM + (size_t)cc * 8;
    float4 a = *(const float4*)(src);
    float4 b = *(const float4*)(src + 4);
    o[0] = (short)f2b(a.x); o[1] = (short)f2b(a.y);
    o[2] = (short)f2b(a.z); o[3] = (short)f2b(a.w);
    o[4] = (short)f2b(b.x); o[5] = (short)f2b(b.y);
    o[6] = (short)f2b(b.z); o[7] = (short)f2b(b.w);
  } else if (cc < 516) {
    int e = cc - 512;
    const float* src = lB + (size_t)e * (D_DIM * 8) + row * 8;
    float4 a = *(const float4*)(src);
    float4 b = *(const float4*)(src + 4);
    o[0] = (short)f2b(a.x); o[1] = (short)f2b(a.y);
    o[2] = (short)f2b(a.z); o[3] = (short)f2b(a.w);
    o[4] = (short)f2b(b.x); o[5] = (short)f2b(b.y);
    o[6] = (short)f2b(b.z); o[7] = (short)f2b(b.w);
  } else {
#pragma unroll
    for (int t = 0; t < 8; ++t) o[t] = 0;
  }
  *(short8*)(wa + row * (size_t)K_DIM + (size_t)cc * 8) = o;
}

// ---- K2b: lora_A (f32 [32][4096]) -> bf16
__global__ __launch_bounds__(256) void cvt_la_k(const float* __restrict__ lA,
                                                short* __restrict__ lAb) {
  size_t i = (size_t)blockIdx.x * 256 + threadIdx.x;   // 16384 chunks of 8
  const float* s = lA + i * 8;
  float4 a = *(const float4*)s;
  float4 b = *(const float4*)(s + 4);
  short8 o;
  o[0] = (short)f2b(a.x); o[1] = (short)f2b(a.y);
  o[2] = (short)f2b(a.z); o[3] = (short)f2b(a.w);
  o[4] = (short)f2b(b.x); o[5] = (short)f2b(b.y);
  o[6] = (short)f2b(b.z); o[7] = (short)f2b(b.w);
  *(short8*)(lAb + i * 8) = o;
}

// ---- K3: gated[b][j] = dot(x[b,L-1,:], gating_W[j,:]) (exact f32 path)
__global__ __launch_bounds__(256) void gated_k(const float* __restrict__ x,
                                               const float* __restrict__ gW,
                                               float* __restrict__ gated) {
  const int j = blockIdx.x;
  const int tid = threadIdx.x;
  float acc[8];
#pragma unroll
  for (int b = 0; b < 8; ++b) acc[b] = 0.f;
  const float* w = gW + (size_t)j * D_DIM;
  for (int i = tid * 4; i < D_DIM; i += 1024) {
    float4 wv = *(const float4*)(w + i);
#pragma unroll
    for (int b = 0; b < 8; ++b) {
      const float* p = x + ((size_t)b * 2048 + 2047) * D_DIM + i;
      float4 pv = *(const float4*)p;
      acc[b] += wv.x * pv.x + wv.y * pv.y + wv.z * pv.z + wv.w * pv.w;
    }
  }
  __shared__ float red[8][4];
  const int lane = tid & 63, wv_ = tid >> 6;
#pragma unroll
  for (int b = 0; b < 8; ++b) {
    float v = acc[b];
    v += __shfl_down(v, 32); v += __shfl_down(v, 16); v += __shfl_down(v, 8);
    v += __shfl_down(v, 4);  v += __shfl_down(v, 2);  v += __shfl_down(v, 1);
    if (lane == 0) red[b][wv_] = v;
  }
  __syncthreads();
  if (tid < 8)
    gated[(size_t)tid * D_DIM + j] = red[tid][0] + red[tid][1] + red[tid][2] + red[tid][3];
}

// ---- K4: logits -> softmax -> module_prob -> top-k gate (1 wave)
__global__ void gate_k(const float* __restrict__ gated, const float* __restrict__ Wr,
                       const float* __restrict__ scores, const int* __restrict__ midx_p,
                       const int* __restrict__ kp, float* __restrict__ gate) {
  const int lane = threadIdx.x;
  float acc[56];
#pragma unroll
  for (int t = 0; t < 56; ++t) acc[t] = 0.f;
  for (int i = lane * 4; i < D_DIM; i += 256) {
    float4 g[8]; float4 w[7];
#pragma unroll
    for (int b = 0; b < 8; ++b) g[b] = *(const float4*)(gated + (size_t)b * D_DIM + i);
#pragma unroll
    for (int m = 0; m < 7; ++m) w[m] = *(const float4*)(Wr + (size_t)m * D_DIM + i);
#pragma unroll
    for (int m = 0; m < 7; ++m)
#pragma unroll
      for (int b = 0; b < 8; ++b)
        acc[m * 8 + b] += w[m].x * g[b].x + w[m].y * g[b].y + w[m].z * g[b].z + w[m].w * g[b].w;
  }
  __shared__ float Ls[56];
#pragma unroll
  for (int t = 0; t < 56; ++t) {
    float v = acc[t];
    v += __shfl_xor(v, 1); v += __shfl_xor(v, 2); v += __shfl_xor(v, 4);
    v += __shfl_xor(v, 8); v += __shfl_xor(v, 16); v += __shfl_xor(v, 32);
    if (lane == t) Ls[t] = v;
  }
  __syncthreads();
  if (lane < 8) {
    const int b = lane;
    float mx = -1e30f;
    for (int m = 0; m < 7; ++m) mx = fmaxf(mx, Ls[m * 8 + b]);
    float s = 0.f;
    for (int m = 0; m < 7; ++m) s += expf(Ls[m * 8 + b] - mx);
    const int mi = midx_p[0];
    const float mp = expf(Ls[mi * 8 + b] - mx) / s;
    int kv = kp[0]; if (kv < 1) kv = 1;
    int klo = kv >> 1; if (klo < 1) klo = 1;
    float sc[4];
#pragma unroll
    for (int e = 0; e < 4; ++e) sc[e] = scores[b * 4 + e];
#pragma unroll
    for (int e = 0; e < 4; ++e) {
      int rank = 0;
#pragma unroll
      for (int e2 = 0; e2 < 4; ++e2)
        rank += (sc[e2] > sc[e] || (sc[e2] == sc[e] && e2 < e)) ? 1 : 0;
      float wv = (mp > 0.5f) ? ((rank < kv) ? 1.0f / (float)kv : 0.f)
                             : ((rank < klo) ? 1.0f / (float)klo : 0.f);
      gate[b * 4 + e] = wv;
    }
  }
}

// ---- K5: LoRA-A projection as MFMA GEMM: t = xa[:, :4096] @ lAb^T  (N=32),
// scaled by gate, written as bf16 into xa cols 4096..4127.
// 256 blocks x 64 rows; 4 waves, each 16 rows x 32 cols. Swizzled LDS.
// FIX vs R2: ALL 4 waves stage B (rows 0..31); wave<2 covered only rows 0..15
// leaving Bs rows 16..31 uninitialized -> NaN.
__global__ __launch_bounds__(256) void lora_t_k(const short* __restrict__ XA,
                                                const short* __restrict__ LAb,
                                                const float* __restrict__ gate,
                                                short* __restrict__ xa_w) {
  __shared__ short As[4096];   // 64 x 64 bf16
  __shared__ short Bs[2048];   // 32 x 64 bf16
  const int tid = threadIdx.x, lane = tid & 63, wave = tid >> 6;
  const int lo = lane & 15, hi = lane >> 4;
  const size_t row0 = (size_t)blockIdx.x * 64;
  const int srow = tid >> 3;                       // 0..31
  const int slot = (tid & 7) ^ (srow & 7);
  const short* gA = XA + (row0 + srow) * (size_t)K_DIM + slot * 8;
  const short* gB = LAb + (size_t)srow * D_DIM + slot * 8;
  f32x4v acc[2] = {};

  for (int t = 0; t < 64; ++t) {
    const int kt = t * 64;
    char* la = (char*)As + wave * 1024;
    char* lb = (char*)Bs + wave * 1024;
    async_copy16(la, gA + kt);                               // A rows 0..31
    async_copy16(la + 4096, gA + (size_t)32 * K_DIM + kt);   // A rows 32..63
    async_copy16(lb, gB + kt);                               // B rows 0..31 (all 4 waves)
    __syncthreads();
    short8 a0 = frag_ld(As, wave * 16 + lo, 0, hi, lo);
    short8 a1 = frag_ld(As, wave * 16 + lo, 1, hi, lo);
    short8 b00 = frag_ld(Bs, lo, 0, hi, lo);
    short8 b01 = frag_ld(Bs, lo, 1, hi, lo);
    short8 b10 = frag_ld(Bs, 16 + lo, 0, hi, lo);
    short8 b11 = frag_ld(Bs, 16 + lo, 1, hi, lo);
    acc[0] = __builtin_amdgcn_mfma_f32_16x16x32_bf16(a0, b00, acc[0], 0, 0, 0);
    acc[0] = __builtin_amdgcn_mfma_f32_16x16x32_bf16(a1, b01, acc[0], 0, 0, 0);
    acc[1] = __builtin_amdgcn_mfma_f32_16x16x32_bf16(a0, b10, acc[1], 0, 0, 0);
    acc[1] = __builtin_amdgcn_mfma_f32_16x16x32_bf16(a1, b11, acc[1], 0, 0, 0);
    __syncthreads();
  }
  const int b = (int)(row0 >> 11);
#pragma unroll
  for (int ni = 0; ni < 2; ++ni) {
    const int col = ni * 16 + lo;
    const float g = gate[b * 4 + (col >> 3)];
#pragma unroll
    for (int j = 0; j < 4; ++j) {
      const size_t r = row0 + wave * 16 + hi * 4 + j;
      xa_w[r * (size_t)K_DIM + 4096 + col] = (short)f2b(acc[ni][j] * g);
    }
  }
}

// ---- K6: main GEMM, 256x256 tile, BK=64, 512 threads (8 waves 2x4).
__global__ __launch_bounds__(512, 2) void gemm_k(const short* __restrict__ A,
                                                 const short* __restrict__ B,
                                                 const float* __restrict__ bias,
                                                 float* __restrict__ C) {
  __shared__ short As[2][16384];   // 2 x 256x64 bf16 (32 KB each)
  __shared__ short Bs[2][16384];
  const int tid = threadIdx.x;
  const int lane = tid & 63;
  const int wave = tid >> 6;            // 0..7
  const int wm = wave >> 2;             // 0..1  -> rows wm*128..+128
  const int wn = wave & 3;              // 0..3  -> cols wn*64..+64
  const int lo = lane & 15, hi = lane >> 4;

  // T1: XCD swizzle (1024 blocks, 8 XCDs, bijective since 1024%8==0)
  const int wg = (blockIdx.x & 7) * 128 + (blockIdx.x >> 3);
  const int brow = wg >> 4;             // 0..63
  const int bcol = wg & 15;             // 0..15

  // staging: load q (0..3): row = q*64 + (tid>>3), phys slot tid&7,
  // logical slot = (tid&7) ^ (row&7)  [row&7 == (tid>>3)&7]
  const int srow = tid >> 3;            // 0..63
  const int slot = (tid & 7) ^ (srow & 7);
  const short* gA = A + (size_t)(brow * 256 + srow) * K_DIM + slot * 8;
  const short* gB = B + (size_t)(bcol * 256 + srow) * K_DIM + slot * 8;

  // bias preload BEFORE any STAGE so its vmcnt events are the oldest and the
  // in-loop counted vmcnt(8) accounting stays exact.
  float bz[4];
#pragma unroll
  for (int ni = 0; ni < 4; ++ni)
    bz[ni] = bias[bcol * 256 + wn * 64 + ni * 16 + lo];

  f32x4v acc[8][4] = {};

#define STAGE(bufi, kt)                                                          \
  {                                                                              \
    char* la_ = (char*)(&As[bufi][0]) + wave * 1024;                             \
    char* lb_ = (char*)(&Bs[bufi][0]) + wave * 1024;                             \
    _Pragma("unroll")                                                            \
    for (int q_ = 0; q_ < 4; ++q_) {                                             \
      async_copy16(la_ + q_ * 8192, gA + (size_t)q_ * 64 * K_DIM + (kt));        \
      async_copy16(lb_ + q_ * 8192, gB + (size_t)q_ * 64 * K_DIM + (kt));        \
    }                                                                            \
  }

#define COMPUTE(bufi)                                                            \
  {                                                                              \
    const short* Ab_ = &As[bufi][0];                                             \
    const short* Bb_ = &Bs[bufi][0];                                             \
    short8 bfr[4][2];                                                            \
    _Pragma("unroll")                                                            \
    for (int ni = 0; ni < 4; ++ni)                                               \
      _Pragma("unroll")                                                          \
      for (int ks = 0; ks < 2; ++ks)                                             \
        bfr[ni][ks] = frag_ld(Bb_, wn * 64 + ni * 16 + lo, ks, hi, lo);          \
    short8 afr[4][2];                                                            \
    _Pragma("unroll")                                                            \
    for (int mi = 0; mi < 4; ++mi)                                               \
      _Pragma("unroll")                                                          \
      for (int ks = 0; ks < 2; ++ks)                                             \
        afr[mi][ks] = frag_ld(Ab_, wm * 128 + mi * 16 + lo, ks, hi, lo);         \
    __builtin_amdgcn_s_setprio(1);                                               \
    _Pragma("unroll")                                                            \
    for (int mi = 0; mi < 4; ++mi)                                               \
      _Pragma("unroll")                                                          \
      for (int ni = 0; ni < 4; ++ni)                                             \
        _Pragma("unroll")                                                        \
        for (int ks = 0; ks < 2; ++ks)                                           \
          acc[mi][ni] = __builtin_amdgcn_mfma_f32_16x16x32_bf16(                 \
              afr[mi][ks], bfr[ni][ks], acc[mi][ni], 0, 0, 0);                   \
    __builtin_amdgcn_s_setprio(0);                                               \
    _Pragma("unroll")                                                            \
    for (int mi = 0; mi < 4; ++mi)                                               \
      _Pragma("unroll")                                                          \
      for (int ks = 0; ks < 2; ++ks)                                             \
        afr[mi][ks] = frag_ld(Ab_, wm * 128 + 64 + mi * 16 + lo, ks, hi, lo);    \
    __builtin_amdgcn_s_setprio(1);                                               \
    _Pragma("unroll")                                                            \
    for (int mi = 0; mi < 4; ++mi)                                               \
      _Pragma("unroll")                                                          \
      for (int ni = 0; ni < 4; ++ni)                                             \
        _Pragma("unroll")                                                        \
        for (int ks = 0; ks < 2; ++ks)                                           \
          acc[mi + 4][ni] = __builtin_amdgcn_mfma_f32_16x16x32_bf16(             \
              afr[mi][ks], bfr[ni][ks], acc[mi + 4][ni], 0, 0, 0);               \
    __builtin_amdgcn_s_setprio(0);                                               \
  }

  STAGE(0, 0);
  for (int t = 0; t < 64; ++t) {
    const int buf = t & 1;
    STAGE(buf ^ 1, (t + 1) * 64);
    asm volatile("s_waitcnt vmcnt(8)" ::: "memory");   // tile t fully landed; t+1 in flight
    __builtin_amdgcn_s_barrier();
    asm volatile("" ::: "memory");
    COMPUTE(buf);
    asm volatile("" ::: "memory");
    __builtin_amdgcn_s_barrier();
    asm volatile("" ::: "memory");
  }
  asm volatile("s_waitcnt vmcnt(0)" ::: "memory");
  __builtin_amdgcn_s_barrier();
  asm volatile("" ::: "memory");
  COMPUTE(0);   // tile 64

#pragma unroll
  for (int mi = 0; mi < 8; ++mi) {
#pragma unroll
    for (int ni = 0; ni < 4; ++ni) {
      const int r0 = brow * 256 + wm * 128 + mi * 16 + hi * 4;
      const int c0 = bcol * 256 + wn * 64 + ni * 16 + lo;
#pragma unroll
      for (int j = 0; j < 4; ++j)
        C[(size_t)(r0 + j) * N_DIM + c0] = acc[mi][ni][j] + bz[ni];
    }
  }
#undef STAGE
#undef COMPUTE
}

extern "C" void kernel_launch(void* const* d_in, const int* in_sizes, int n_in,
                              void* d_out, int out_size, void* d_ws, size_t ws_size,
                              hipStream_t stream) {
  const float* x      = (const float*)d_in[0];
  const float* scores = (const float*)d_in[1];
  const float* Wb     = (const float*)d_in[2];
  const float* bb     = (const float*)d_in[3];
  const float* gW     = (const float*)d_in[4];
  const float* Wr     = (const float*)d_in[5];
  const float* lA     = (const float*)d_in[6];
  const float* lB     = (const float*)d_in[7];
  const int*   midx   = (const int*)d_in[8];
  const int*   kk     = (const int*)d_in[9];
  float* out = (float*)d_out;

  char* ws = (char*)d_ws;
  short* xa    = (short*)ws;                                        // 136,314,880 B
  short* wa    = (short*)(ws + 136314880u);                         //  34,078,720 B
  float* gated = (float*)(ws + 136314880u + 34078720u);             //     131,072 B
  float* gate  = (float*)(ws + 136314880u + 34078720u + 131072u);   //         128 B
  short* lAb   = (short*)(ws + 136314880u + 34078720u + 131072u + 128u);  // 262,144 B

  cvt_x_k<<<33280, 256, 0, stream>>>(x, xa);
  cvt_w_k<<<8320, 256, 0, stream>>>(Wb, lB, wa);
  cvt_la_k<<<64, 256, 0, stream>>>(lA, lAb);
  gated_k<<<4096, 256, 0, stream>>>(x, gW, gated);
  gate_k<<<1, 64, 0, stream>>>(gated, Wr, scores, midx, kk, gate);
  lora_t_k<<<256, 256, 0, stream>>>(xa, lAb, gate, xa);
  gemm_k<<<1024, 512, 0, stream>>>(xa, wa, bb, out);
}